// Round 5
// baseline (534.191 us; speedup 1.0000x reference)
//
#include <hip/hip_runtime.h>

typedef __attribute__((ext_vector_type(8))) short short8;
typedef __attribute__((ext_vector_type(4))) float floatx4;
typedef __attribute__((ext_vector_type(16))) float floatx16;
typedef __attribute__((ext_vector_type(4))) int intx4;

#define NPIX 4096
#define CH 256

static __device__ __forceinline__ unsigned short f2bf(float f) {
  union { float f; unsigned int u; } v; v.f = f;
  unsigned int u = v.u;
  return (unsigned short)((u + 0x7FFFu + ((u >> 16) & 1u)) >> 16);
}

// pack bf16(a) | bf16(b)<<16 : 3 VALU ops (2 int-add round + 1 v_perm)
static __device__ __forceinline__ unsigned int pk2bf(float a, float b) {
  union { float f; unsigned int u; } x, y; x.f = a; y.f = b;
  return __builtin_amdgcn_perm(y.u + 0x8000u, x.u + 0x8000u, 0x07060302u);
}

typedef __attribute__((address_space(3))) unsigned int lds_uint;
typedef const __attribute__((address_space(1))) unsigned int glob_uint;
static __device__ __forceinline__ void gload16(const void* g, void* l) {
  __builtin_amdgcn_global_load_lds((glob_uint*)g, (lds_uint*)l, 16, 0, 0);
}

// ---------------- weights fp32 -> bf16 ----------------
__global__ void conv_weights_kernel(const float* __restrict__ wq, const float* __restrict__ wk,
                                    const float* __restrict__ wv, const float* __restrict__ wo,
                                    unsigned short* __restrict__ wqkv, unsigned short* __restrict__ wob) {
  int i = blockIdx.x * 256 + threadIdx.x;   // 0..65535
  wqkv[i]          = f2bf(wq[i]);
  wqkv[65536 + i]  = f2bf(wk[i]);
  wqkv[131072 + i] = f2bf(wv[i]);
  wob[i]           = f2bf(wo[i]);
}

// ---------------- GroupNorm -> xnT bf16 [b][n][c] ----------------
__global__ __launch_bounds__(256) void gn_kernel(const float* __restrict__ x,
                                                 const float* __restrict__ gsc,
                                                 const float* __restrict__ gbi,
                                                 unsigned short* __restrict__ xnT) {
  int blk = blockIdx.x; int b = blk >> 5; int g = blk & 31;
  int c0 = g * 8;
  const float* xb = x + ((size_t)b * CH + c0) * NPIX;
  int tid = threadIdx.x;
  float s = 0.f, ss = 0.f;
#pragma unroll
  for (int ci = 0; ci < 8; ++ci) {
    const floatx4* p = (const floatx4*)(xb + (size_t)ci * NPIX);
    for (int n4 = tid; n4 < 1024; n4 += 256) {
      floatx4 v = p[n4];
      s += v[0] + v[1] + v[2] + v[3];
      ss += v[0]*v[0] + v[1]*v[1] + v[2]*v[2] + v[3]*v[3];
    }
  }
#pragma unroll
  for (int o = 32; o > 0; o >>= 1) { s += __shfl_down(s, o); ss += __shfl_down(ss, o); }
  __shared__ float red[10];
  int wid = tid >> 6;
  if ((tid & 63) == 0) { red[wid] = s; red[4 + wid] = ss; }
  __syncthreads();
  if (tid == 0) {
    float S = red[0] + red[1] + red[2] + red[3];
    float SS = red[4] + red[5] + red[6] + red[7];
    float mean = S * (1.f / 32768.f);
    float var = SS * (1.f / 32768.f) - mean * mean;
    red[8] = mean; red[9] = rsqrtf(var + 1e-5f);
  }
  __syncthreads();
  float mean = red[8], rstd = red[9];
  float sc[8], bi[8];
#pragma unroll
  for (int ci = 0; ci < 8; ++ci) {
    float scale = gsc[c0 + ci] * rstd;
    sc[ci] = scale;
    bi[ci] = gbi[c0 + ci] - mean * scale;
  }
  for (int n4 = tid; n4 < 1024; n4 += 256) {
    floatx4 v[8];
#pragma unroll
    for (int ci = 0; ci < 8; ++ci) v[ci] = ((const floatx4*)(xb + (size_t)ci * NPIX))[n4];
#pragma unroll
    for (int j = 0; j < 4; ++j) {
      alignas(16) unsigned short tmp[8];
#pragma unroll
      for (int ci = 0; ci < 8; ++ci) tmp[ci] = f2bf(v[ci][j] * sc[ci] + bi[ci]);
      *(intx4*)(xnT + ((size_t)(b * NPIX + n4 * 4 + j)) * CH + c0) = *(const intx4*)tmp;
    }
  }
}

// ---------------- QKV GEMM: D[o,n] = sum_c W[o,c]*xnT[n,c] + bias ----------------
// q pre-scaled by log2e/16 ; q,k written [n][o] bf16 ; v written [o][n] bf16
__global__ __launch_bounds__(256, 2) void qkv_gemm(
    const unsigned short* __restrict__ wqkv, const unsigned short* __restrict__ xnT,
    const float* __restrict__ bq, const float* __restrict__ bk, const float* __restrict__ bv,
    unsigned short* __restrict__ qT, unsigned short* __restrict__ kT, unsigned short* __restrict__ vC) {
  int nt = blockIdx.x, ot = blockIdx.y, bz = blockIdx.z;
  int which = bz % 3, b = bz / 3;
  const unsigned short* W = wqkv + which * 65536;
  const float* bias = which == 0 ? bq : (which == 1 ? bk : bv);
  const unsigned short* X = xnT + (size_t)b * NPIX * CH;
  int o0 = ot * 128, n0 = nt * 128;

  __shared__ unsigned short As[128 * 64];
  __shared__ unsigned short Bs[128 * 64];

  int tid = threadIdx.x;
  int wave = tid >> 6, lane = tid & 63, quad = lane >> 4, l16 = lane & 15;
  int wm = (wave >> 1) * 64, wn = (wave & 1) * 64;

  floatx4 acc[4][4];
#pragma unroll
  for (int i = 0; i < 4; ++i)
#pragma unroll
    for (int j = 0; j < 4; ++j) acc[i][j] = (floatx4){0.f, 0.f, 0.f, 0.f};

  for (int k0 = 0; k0 < 256; k0 += 64) {
    __syncthreads();
#pragma unroll
    for (int c2 = 0; c2 < 4; ++c2) {
      int row = wave * 32 + c2 * 8 + (lane >> 3);
      int sc = (lane & 7) ^ (row & 7);
      gload16(W + (size_t)(o0 + row) * CH + k0 + sc * 8, &As[(wave * 32 + c2 * 8) * 64]);
      gload16(X + (size_t)(n0 + row) * CH + k0 + sc * 8, &Bs[(wave * 32 + c2 * 8) * 64]);
    }
    __syncthreads();
#pragma unroll
    for (int s = 0; s < 2; ++s) {
      short8 af[4], bf[4];
#pragma unroll
      for (int i = 0; i < 4; ++i) {
        int m = wm + i * 16 + l16;
        af[i] = *(const short8*)(As + m * 64 + (((s * 4 + quad) ^ (m & 7)) * 8));
        int n = wn + i * 16 + l16;
        bf[i] = *(const short8*)(Bs + n * 64 + (((s * 4 + quad) ^ (n & 7)) * 8));
      }
#pragma unroll
      for (int i = 0; i < 4; ++i)
#pragma unroll
        for (int j = 0; j < 4; ++j)
          acc[i][j] = __builtin_amdgcn_mfma_f32_16x16x32_bf16(af[i], bf[j], acc[i][j], 0, 0, 0);
    }
  }

  if (which < 2) {
    // 0.0625 * log2(e)
    float qs = (which == 0) ? 0.090168440f : 1.0f;
    unsigned short* outp = (which == 0 ? qT : kT) + (size_t)b * NPIX * CH;
#pragma unroll
    for (int i = 0; i < 4; ++i) {
      int obase = o0 + wm + i * 16 + quad * 4;
      float bias4[4];
#pragma unroll
      for (int r = 0; r < 4; ++r) bias4[r] = bias[obase + r];
#pragma unroll
      for (int j = 0; j < 4; ++j) {
        int n = n0 + wn + j * 16 + l16;
        uint2 pk;
        pk.x = pk2bf((acc[i][j][0] + bias4[0]) * qs, (acc[i][j][1] + bias4[1]) * qs);
        pk.y = pk2bf((acc[i][j][2] + bias4[2]) * qs, (acc[i][j][3] + bias4[3]) * qs);
        *(uint2*)(outp + (size_t)n * CH + obase) = pk;
      }
    }
  } else {
    unsigned short* outp = vC + (size_t)b * CH * NPIX;
#pragma unroll
    for (int i = 0; i < 4; ++i)
#pragma unroll
      for (int r = 0; r < 4; ++r) {
        int o = o0 + wm + i * 16 + quad * 4 + r;
        float bb = bias[o];
#pragma unroll
        for (int j = 0; j < 4; ++j) {
          int n = n0 + wn + j * 16 + l16;
          outp[(size_t)o * NPIX + n] = f2bf(acc[i][j][r] + bb);
        }
      }
  }
}

// ---------------- fused attention: 1 block/CU, 8 waves, q-tile 128, KTILE=128 ----------
// Round-5 fix over round 4: V register loads are issued at the TOP of the iteration,
// BEFORE STAGE_K. vmcnt is a FIFO: in round 4 the vf loads were issued in phase 2
// (after STAGE_K), so waiting for vf forced the K-prefetch to drain mid-iteration and
// exposed raw L2 gather latency on the MFMA path (MfmaUtil 33->23.7). With vf oldest:
//   - phase-2 waits for vf leave the 8 K-stage loads outstanding (no drain),
//   - vf L2 latency hides under ALL of phase 1,
//   - barrier B's vmcnt(0) waits on iteration-old K loads = ~free.
// LDS = Klds[2][128*256] (128KB) + Plds[128*128] (32KB) = 160KB exactly.
// LDS traffic/iter: kf 256KB + pf 128KB + P-wr 32KB + K-stage-wr 64KB = 480KB.
// Phase1 (S^T = K·Q^T): roles 2 m-pairs(64) x 4 q-slices(32); qf[16] in registers.
// Phase2 (O^T += V·P^T): roles 4 c-slices(64) x 2 q-halves(64); vf in registers.
// Register budget: qf 64 + vf 64 + s0/s1 32 + oacc 64 + addr ~16 = ~240 < 256 cap.
// Spill tripwire = WRITE_SIZE (16.4MB clean; >17MB means scratch).
// Swizzles: K rows 512B=32 chunks -> ^(row&31); P rows 256B=16 chunks -> ^(row&15).
// 32x32x16 layouts: A[m=lane&31][k=(lane>>5)*8+j]; B[k][n=lane&31]; D col=lane&31,
// row=(r&3)+8*(r>>2)+4*(lane>>5).
__global__ __launch_bounds__(512, 2) void attn_kernel(
    const unsigned short* __restrict__ qT, const unsigned short* __restrict__ kT,
    const unsigned short* __restrict__ vC, unsigned short* __restrict__ aT) {
  __shared__ unsigned short Klds[2][128 * 256];  // 2 x 64KB [m][c], XOR-32 swizzle
  __shared__ unsigned short Plds[128 * 128];     // 32KB [q][m], XOR-16 swizzle
  // total 160KB exactly; lred reuses Plds after the main loop.

  const int tid = threadIdx.x;
  const int w = tid >> 6, lane = tid & 63;
  const int l32 = lane & 31, h = lane >> 5;
  const int b = blockIdx.x & 7, qt = blockIdx.x >> 3;
  const int qbase = qt * 128;

  const unsigned short* Kb = kT + (size_t)b * NPIX * CH;
  const unsigned short* Vb = vC + (size_t)b * CH * NPIX;

  const int mp  = (w & 1) * 64;   // phase-1 m-pair base (covers [mp, mp+64))
  const int qsl = (w >> 1) * 32;  // phase-1 q-slice
  const int csl = (w & 3) * 64;   // phase-2 c-slice base
  const int qp  = (w >> 2) * 64;  // phase-2 q-half

  // Q fragments (B-operand): q = qbase+qsl+l32, k=c = ks*16 + h*8 + j  (64 VGPRs)
  short8 qf[16];
  {
    const unsigned short* qq = qT + ((size_t)(b * NPIX + qbase + qsl + l32)) * CH + h * 8;
#pragma unroll
    for (int ks = 0; ks < 16; ++ks) qf[ks] = *(const short8*)(qq + ks * 16);
  }

  // phase-2 V row pointers (A-operand rows, 16B-contiguous per fragment)
  const unsigned short* vrow0 = Vb + (size_t)(csl + l32) * NPIX + h * 8;
  const unsigned short* vrow1 = Vb + (size_t)(csl + 32 + l32) * NPIX + h * 8;

  floatx16 o00 = {}, o01 = {}, o10 = {}, o11 = {};  // [csub][qsub] D[c][q]
  float l_acc = 0.f;

  // K tile stage: 128 rows x 512B; per wave 16 rows (2 rows / gload16, lanes 0-31 row r,
  // lanes 32-63 row r+1); lane's physical chunk = l32; source pre-swizzled so
  // LDS[row][phys] = K[row][phys ^ (row&31)].
#define STAGE_K(KT, BUF)                                                         \
  {                                                                              \
    int m0_ = (KT) * 128;                                                        \
    _Pragma("unroll") for (int j = 0; j < 8; ++j) {                              \
      int r_ = w * 16 + j * 2 + h;                                               \
      gload16(Kb + (size_t)(m0_ + r_) * CH + ((l32 ^ (r_ & 31)) * 8),            \
              &Klds[BUF][(w * 16 + j * 2) * 256]);                               \
    }                                                                            \
  }

  STAGE_K(0, 0);
  asm volatile("s_waitcnt vmcnt(0)\ns_barrier" ::: "memory");

  for (int kt = 0; kt < 32; ++kt) {
    const int buf = kt & 1;

    // ---- V(kt) register loads: ISSUED FIRST (oldest VMEM of the iter) ----
    short8 vf0[8], vf1[8];
    {
      const unsigned short* v0p = vrow0 + kt * 128;
      const unsigned short* v1p = vrow1 + kt * 128;
#pragma unroll
      for (int ks = 0; ks < 8; ++ks) {
        vf0[ks] = *(const short8*)(v0p + ks * 16);
        vf1[ks] = *(const short8*)(v1p + ks * 16);
      }
    }
    // K(kt+1) staging: issued AFTER vf -> waits on vf never drain these
    if (kt + 1 < 32) STAGE_K(kt + 1, buf ^ 1);

    // ---- phase 1: S^T tiles D[m 64][q 32] (two 32x32 m-subtiles, shared qf) ----
    floatx16 s0 = {}, s1 = {};
    {
      const unsigned short* kr0 = &Klds[buf][(mp + l32) * 256];
      const unsigned short* kr1 = &Klds[buf][(mp + 32 + l32) * 256];
      const int mx = l32;   // (mp+l32)&31 == (mp+32+l32)&31 == l32  (mp in {0,64})
#pragma unroll
      for (int ks = 0; ks < 16; ++ks) {
        int off = ((ks * 2 + h) ^ mx) * 8;
        short8 kf0 = *(const short8*)(kr0 + off);
        short8 kf1 = *(const short8*)(kr1 + off);
        s0 = __builtin_amdgcn_mfma_f32_32x32x16_bf16(kf0, qf[ks], s0, 0, 0, 0);
        s1 = __builtin_amdgcn_mfma_f32_32x32x16_bf16(kf1, qf[ks], s1, 0, 0, 0);
      }
    }
    // exp2 + l partial sum (both m-subtiles share q = l32; h-halves differ in m)
    float sum = 0.f;
#pragma unroll
    for (int r = 0; r < 16; ++r) {
      float p0 = exp2f(s0[r]); s0[r] = p0; sum += p0;
      float p1 = exp2f(s1[r]); s1[r] = p1; sum += p1;
    }
    sum += __shfl_xor(sum, 32);
    l_acc += sum;

    // P -> LDS: lane holds (q = qsl+l32, m = mp + sub*32 + 8t + 4h + i) for reg r = 4t+i
    // physical chunk = (logical m-chunk) ^ (q & 15)
    {
      int qrow = qsl + l32;
      int qx = qrow & 15;
      char* Pq = (char*)Plds + qrow * 256 + h * 8;
      int g0 = (w & 1) * 8;   // logical 16B chunk base within the 128-m row
#pragma unroll
      for (int t = 0; t < 4; ++t) {
        uint2 wv;
        wv.x = pk2bf(s0[4 * t], s0[4 * t + 1]);
        wv.y = pk2bf(s0[4 * t + 2], s0[4 * t + 3]);
        *(uint2*)(Pq + (((g0 + t) ^ qx) * 16)) = wv;
        wv.x = pk2bf(s1[4 * t], s1[4 * t + 1]);
        wv.y = pk2bf(s1[4 * t + 2], s1[4 * t + 3]);
        *(uint2*)(Pq + (((g0 + 4 + t) ^ qx) * 16)) = wv;
      }
    }
    // barrier A: P visible (lgkm only). K(kt+1) staging stays IN FLIGHT across this.
    asm volatile("s_waitcnt lgkmcnt(0)\ns_barrier" ::: "memory");

    // ---- phase 2: O^T += V P^T, wave tile D[c 64][q 64]; vf already in registers ----
    {
      const int q0 = qp + l32, q1 = qp + 32 + l32;
      const char* Pb = (const char*)Plds;
#pragma unroll
      for (int ks = 0; ks < 8; ++ks) {
        int sl = ks * 2 + h;
        short8 pf0 = *(const short8*)(Pb + q0 * 256 + ((sl ^ (q0 & 15)) * 16));
        short8 pf1 = *(const short8*)(Pb + q1 * 256 + ((sl ^ (q1 & 15)) * 16));
        o00 = __builtin_amdgcn_mfma_f32_32x32x16_bf16(vf0[ks], pf0, o00, 0, 0, 0);
        o01 = __builtin_amdgcn_mfma_f32_32x32x16_bf16(vf0[ks], pf1, o01, 0, 0, 0);
        o10 = __builtin_amdgcn_mfma_f32_32x32x16_bf16(vf1[ks], pf0, o10, 0, 0, 0);
        o11 = __builtin_amdgcn_mfma_f32_32x32x16_bf16(vf1[ks], pf1, o11, 0, 0, 0);
      }
    }
    // barrier B: P(kt) reads done (next iter rewrites P); K(kt+1) landed (vmcnt(0)
    // waits on loads issued a whole iteration ago -> ~zero stall).
    asm volatile("s_waitcnt vmcnt(0) lgkmcnt(0)\ns_barrier" ::: "memory");
  }
#undef STAGE_K

  // ---- l reconciliation across the 2 m-pair waves per q-slice (Plds -> float[q][2]) ----
  float* lred = (float*)Plds;
  if (lane < 32) lred[(qsl + l32) * 2 + (w & 1)] = l_acc;
  __syncthreads();
  float inv0, inv1;
  {
    const float* lp0 = &lred[(qp + l32) * 2];
    inv0 = 1.f / (lp0[0] + lp0[1]);
    const float* lp1 = &lred[(qp + 32 + l32) * 2];
    inv1 = 1.f / (lp1[0] + lp1[1]);
  }

  // ---- store O^T -> aT[q][c] bf16 (explicit accumulators, no array: avoids scratch) ----
  unsigned short* ab = aT + (size_t)b * NPIX * CH;
#define STORE_TILE(OO, CSUB, QSUB, IV)                                           \
  {                                                                              \
    int qg = qbase + qp + (QSUB) * 32 + l32;                                     \
    _Pragma("unroll") for (int t = 0; t < 4; ++t) {                              \
      int c = csl + (CSUB) * 32 + 8 * t + 4 * h;                                 \
      uint2 wv;                                                                  \
      wv.x = pk2bf(OO[4 * t] * (IV), OO[4 * t + 1] * (IV));                      \
      wv.y = pk2bf(OO[4 * t + 2] * (IV), OO[4 * t + 3] * (IV));                  \
      *(uint2*)(ab + (size_t)qg * CH + c) = wv;                                  \
    }                                                                            \
  }
  STORE_TILE(o00, 0, 0, inv0)
  STORE_TILE(o01, 0, 1, inv1)
  STORE_TILE(o10, 1, 0, inv0)
  STORE_TILE(o11, 1, 1, inv1)
#undef STORE_TILE
}

// ---------------- output projection + bias + residual ----------------
__global__ __launch_bounds__(256, 2) void out_gemm(
    const unsigned short* __restrict__ wob, const unsigned short* __restrict__ aT,
    const float* __restrict__ bo, const float* __restrict__ x, float* __restrict__ outp) {
  int nt = blockIdx.x, ot = blockIdx.y, b = blockIdx.z;
  const unsigned short* A = aT + (size_t)b * NPIX * CH;
  int o0 = ot * 128, n0 = nt * 128;

  __shared__ unsigned short As[128 * 64];
  __shared__ unsigned short Bs[128 * 64];

  int tid = threadIdx.x;
  int wave = tid >> 6, lane = tid & 63, quad = lane >> 4, l16 = lane & 15;
  int wm = (wave >> 1) * 64, wn = (wave & 1) * 64;

  floatx4 acc[4][4];
#pragma unroll
  for (int i = 0; i < 4; ++i)
#pragma unroll
    for (int j = 0; j < 4; ++j) acc[i][j] = (floatx4){0.f, 0.f, 0.f, 0.f};

  for (int k0 = 0; k0 < 256; k0 += 64) {
    __syncthreads();
#pragma unroll
    for (int c2 = 0; c2 < 4; ++c2) {
      int row = wave * 32 + c2 * 8 + (lane >> 3);
      int sc = (lane & 7) ^ (row & 7);
      gload16(wob + (size_t)(o0 + row) * CH + k0 + sc * 8, &As[(wave * 32 + c2 * 8) * 64]);
      gload16(A + (size_t)(n0 + row) * CH + k0 + sc * 8, &Bs[(wave * 32 + c2 * 8) * 64]);
    }
    __syncthreads();
#pragma unroll
    for (int s = 0; s < 2; ++s) {
      short8 af[4], bf[4];
#pragma unroll
      for (int i = 0; i < 4; ++i) {
        int m = wm + i * 16 + l16;
        af[i] = *(const short8*)(As + m * 64 + (((s * 4 + quad) ^ (m & 7)) * 8));
        int n = wn + i * 16 + l16;
        bf[i] = *(const short8*)(Bs + n * 64 + (((s * 4 + quad) ^ (n & 7)) * 8));
      }
#pragma unroll
      for (int i = 0; i < 4; ++i)
#pragma unroll
        for (int j = 0; j < 4; ++j)
          acc[i][j] = __builtin_amdgcn_mfma_f32_16x16x32_bf16(af[i], bf[j], acc[i][j], 0, 0, 0);
    }
  }

#pragma unroll
  for (int i = 0; i < 4; ++i)
#pragma unroll
    for (int r = 0; r < 4; ++r) {
      int o = o0 + wm + i * 16 + quad * 4 + r;
      float bb = bo[o];
#pragma unroll
      for (int j = 0; j < 4; ++j) {
        int n = n0 + wn + j * 16 + l16;
        size_t idx = ((size_t)b * CH + o) * NPIX + n;
        outp[idx] = x[idx] + bb + acc[i][j][r];
      }
    }
}

extern "C" void kernel_launch(void* const* d_in, const int* in_sizes, int n_in,
                              void* d_out, int out_size, void* d_ws, size_t ws_size,
                              hipStream_t stream) {
  const float* x   = (const float*)d_in[0];
  const float* gsc = (const float*)d_in[1];
  const float* gbi = (const float*)d_in[2];
  const float* wq  = (const float*)d_in[3];
  const float* bq  = (const float*)d_in[4];
  const float* wk  = (const float*)d_in[5];
  const float* bk  = (const float*)d_in[6];
  const float* wv  = (const float*)d_in[7];
  const float* bv  = (const float*)d_in[8];
  const float* wo  = (const float*)d_in[9];
  const float* bo  = (const float*)d_in[10];
  float* out = (float*)d_out;

  char* ws = (char*)d_ws;
  unsigned short* xnT  = (unsigned short*)(ws);              // 16 MB (dead after qkv)
  unsigned short* qT   = (unsigned short*)(ws + 16777216);   // 16 MB
  unsigned short* kT   = (unsigned short*)(ws + 33554432);   // 16 MB
  unsigned short* vC   = (unsigned short*)(ws + 50331648);   // 16 MB
  unsigned short* wqkv = (unsigned short*)(ws + 67108864);   // 384 KB
  unsigned short* wob  = (unsigned short*)(ws + 67502080);   // 128 KB
  unsigned short* aT   = (unsigned short*)(ws + 67633152);   // 16 MB

  conv_weights_kernel<<<256, 256, 0, stream>>>(wq, wk, wv, wo, wqkv, wob);
  gn_kernel<<<256, 256, 0, stream>>>(x, gsc, gbi, xnT);
  dim3 g1(32, 2, 24);
  qkv_gemm<<<g1, 256, 0, stream>>>(wqkv, xnT, bq, bk, bv, qT, kT, vC);
  attn_kernel<<<256, 512, 0, stream>>>(qT, kT, vC, aT);
  dim3 g3(32, 2, 8);
  out_gemm<<<g3, 256, 0, stream>>>(wob, aT, bo, x, out);
}

// Round 6
// 517.193 us; speedup vs baseline: 1.0329x; 1.0329x over previous
//
#include <hip/hip_runtime.h>

typedef __attribute__((ext_vector_type(8))) short short8;
typedef __attribute__((ext_vector_type(4))) float floatx4;
typedef __attribute__((ext_vector_type(16))) float floatx16;
typedef __attribute__((ext_vector_type(4))) int intx4;

#define NPIX 4096
#define CH 256

static __device__ __forceinline__ unsigned short f2bf(float f) {
  union { float f; unsigned int u; } v; v.f = f;
  unsigned int u = v.u;
  return (unsigned short)((u + 0x7FFFu + ((u >> 16) & 1u)) >> 16);
}

// pack bf16(a) | bf16(b)<<16 : 3 VALU ops (2 int-add round + 1 v_perm)
static __device__ __forceinline__ unsigned int pk2bf(float a, float b) {
  union { float f; unsigned int u; } x, y; x.f = a; y.f = b;
  return __builtin_amdgcn_perm(y.u + 0x8000u, x.u + 0x8000u, 0x07060302u);
}

typedef __attribute__((address_space(3))) unsigned int lds_uint;
typedef const __attribute__((address_space(1))) unsigned int glob_uint;
static __device__ __forceinline__ void gload16(const void* g, void* l) {
  __builtin_amdgcn_global_load_lds((glob_uint*)g, (lds_uint*)l, 16, 0, 0);
}

// ---------------- weights fp32 -> bf16 ----------------
__global__ void conv_weights_kernel(const float* __restrict__ wq, const float* __restrict__ wk,
                                    const float* __restrict__ wv, const float* __restrict__ wo,
                                    unsigned short* __restrict__ wqkv, unsigned short* __restrict__ wob) {
  int i = blockIdx.x * 256 + threadIdx.x;   // 0..65535
  wqkv[i]          = f2bf(wq[i]);
  wqkv[65536 + i]  = f2bf(wk[i]);
  wqkv[131072 + i] = f2bf(wv[i]);
  wob[i]           = f2bf(wo[i]);
}

// ---------------- GroupNorm -> xnT bf16 [b][n][c] ----------------
__global__ __launch_bounds__(256) void gn_kernel(const float* __restrict__ x,
                                                 const float* __restrict__ gsc,
                                                 const float* __restrict__ gbi,
                                                 unsigned short* __restrict__ xnT) {
  int blk = blockIdx.x; int b = blk >> 5; int g = blk & 31;
  int c0 = g * 8;
  const float* xb = x + ((size_t)b * CH + c0) * NPIX;
  int tid = threadIdx.x;
  float s = 0.f, ss = 0.f;
#pragma unroll
  for (int ci = 0; ci < 8; ++ci) {
    const floatx4* p = (const floatx4*)(xb + (size_t)ci * NPIX);
    for (int n4 = tid; n4 < 1024; n4 += 256) {
      floatx4 v = p[n4];
      s += v[0] + v[1] + v[2] + v[3];
      ss += v[0]*v[0] + v[1]*v[1] + v[2]*v[2] + v[3]*v[3];
    }
  }
#pragma unroll
  for (int o = 32; o > 0; o >>= 1) { s += __shfl_down(s, o); ss += __shfl_down(ss, o); }
  __shared__ float red[10];
  int wid = tid >> 6;
  if ((tid & 63) == 0) { red[wid] = s; red[4 + wid] = ss; }
  __syncthreads();
  if (tid == 0) {
    float S = red[0] + red[1] + red[2] + red[3];
    float SS = red[4] + red[5] + red[6] + red[7];
    float mean = S * (1.f / 32768.f);
    float var = SS * (1.f / 32768.f) - mean * mean;
    red[8] = mean; red[9] = rsqrtf(var + 1e-5f);
  }
  __syncthreads();
  float mean = red[8], rstd = red[9];
  float sc[8], bi[8];
#pragma unroll
  for (int ci = 0; ci < 8; ++ci) {
    float scale = gsc[c0 + ci] * rstd;
    sc[ci] = scale;
    bi[ci] = gbi[c0 + ci] - mean * scale;
  }
  for (int n4 = tid; n4 < 1024; n4 += 256) {
    floatx4 v[8];
#pragma unroll
    for (int ci = 0; ci < 8; ++ci) v[ci] = ((const floatx4*)(xb + (size_t)ci * NPIX))[n4];
#pragma unroll
    for (int j = 0; j < 4; ++j) {
      alignas(16) unsigned short tmp[8];
#pragma unroll
      for (int ci = 0; ci < 8; ++ci) tmp[ci] = f2bf(v[ci][j] * sc[ci] + bi[ci]);
      *(intx4*)(xnT + ((size_t)(b * NPIX + n4 * 4 + j)) * CH + c0) = *(const intx4*)tmp;
    }
  }
}

// ---------------- QKV GEMM: D[o,n] = sum_c W[o,c]*xnT[n,c] + bias ----------------
// q pre-scaled by log2e/16 ; q,k written [n][o] bf16 ; v written [o][n] bf16
__global__ __launch_bounds__(256, 2) void qkv_gemm(
    const unsigned short* __restrict__ wqkv, const unsigned short* __restrict__ xnT,
    const float* __restrict__ bq, const float* __restrict__ bk, const float* __restrict__ bv,
    unsigned short* __restrict__ qT, unsigned short* __restrict__ kT, unsigned short* __restrict__ vC) {
  int nt = blockIdx.x, ot = blockIdx.y, bz = blockIdx.z;
  int which = bz % 3, b = bz / 3;
  const unsigned short* W = wqkv + which * 65536;
  const float* bias = which == 0 ? bq : (which == 1 ? bk : bv);
  const unsigned short* X = xnT + (size_t)b * NPIX * CH;
  int o0 = ot * 128, n0 = nt * 128;

  __shared__ unsigned short As[128 * 64];
  __shared__ unsigned short Bs[128 * 64];

  int tid = threadIdx.x;
  int wave = tid >> 6, lane = tid & 63, quad = lane >> 4, l16 = lane & 15;
  int wm = (wave >> 1) * 64, wn = (wave & 1) * 64;

  floatx4 acc[4][4];
#pragma unroll
  for (int i = 0; i < 4; ++i)
#pragma unroll
    for (int j = 0; j < 4; ++j) acc[i][j] = (floatx4){0.f, 0.f, 0.f, 0.f};

  for (int k0 = 0; k0 < 256; k0 += 64) {
    __syncthreads();
#pragma unroll
    for (int c2 = 0; c2 < 4; ++c2) {
      int row = wave * 32 + c2 * 8 + (lane >> 3);
      int sc = (lane & 7) ^ (row & 7);
      gload16(W + (size_t)(o0 + row) * CH + k0 + sc * 8, &As[(wave * 32 + c2 * 8) * 64]);
      gload16(X + (size_t)(n0 + row) * CH + k0 + sc * 8, &Bs[(wave * 32 + c2 * 8) * 64]);
    }
    __syncthreads();
#pragma unroll
    for (int s = 0; s < 2; ++s) {
      short8 af[4], bf[4];
#pragma unroll
      for (int i = 0; i < 4; ++i) {
        int m = wm + i * 16 + l16;
        af[i] = *(const short8*)(As + m * 64 + (((s * 4 + quad) ^ (m & 7)) * 8));
        int n = wn + i * 16 + l16;
        bf[i] = *(const short8*)(Bs + n * 64 + (((s * 4 + quad) ^ (n & 7)) * 8));
      }
#pragma unroll
      for (int i = 0; i < 4; ++i)
#pragma unroll
        for (int j = 0; j < 4; ++j)
          acc[i][j] = __builtin_amdgcn_mfma_f32_16x16x32_bf16(af[i], bf[j], acc[i][j], 0, 0, 0);
    }
  }

  if (which < 2) {
    // 0.0625 * log2(e)
    float qs = (which == 0) ? 0.090168440f : 1.0f;
    unsigned short* outp = (which == 0 ? qT : kT) + (size_t)b * NPIX * CH;
#pragma unroll
    for (int i = 0; i < 4; ++i) {
      int obase = o0 + wm + i * 16 + quad * 4;
      float bias4[4];
#pragma unroll
      for (int r = 0; r < 4; ++r) bias4[r] = bias[obase + r];
#pragma unroll
      for (int j = 0; j < 4; ++j) {
        int n = n0 + wn + j * 16 + l16;
        uint2 pk;
        pk.x = pk2bf((acc[i][j][0] + bias4[0]) * qs, (acc[i][j][1] + bias4[1]) * qs);
        pk.y = pk2bf((acc[i][j][2] + bias4[2]) * qs, (acc[i][j][3] + bias4[3]) * qs);
        *(uint2*)(outp + (size_t)n * CH + obase) = pk;
      }
    }
  } else {
    unsigned short* outp = vC + (size_t)b * CH * NPIX;
#pragma unroll
    for (int i = 0; i < 4; ++i)
#pragma unroll
      for (int r = 0; r < 4; ++r) {
        int o = o0 + wm + i * 16 + quad * 4 + r;
        float bb = bias[o];
#pragma unroll
        for (int j = 0; j < 4; ++j) {
          int n = n0 + wn + j * 16 + l16;
          outp[(size_t)o * NPIX + n] = f2bf(acc[i][j][r] + bb);
        }
      }
  }
}

// ---------------- fused attention: 2 blocks/CU, 4 waves, q-tile 64, KTILE=128 ---------
// Round-6 thesis: every prior structure was latency/sync-bound at 1 block/CU (Occupancy
// ~22%, all pipes <50%). Halve the block so TWO blocks co-reside per CU (independent
// barrier domains): block B's waves run while block A drains/exp2s/waits.
//   grid 512: b = bid&7 (XCD-pinned), qt = bid>>3 (0..63), q-tile 64.
//   LDS = Klds[128*256] 64KB + Plds[64*128] 16KB = 80KB EXACTLY -> 2 blocks/CU.
// Per iter (32 iters): phase1 (roles 2 m-pairs x 2 q-slices, 32 MFMA/wave) ->
//   softmax -> P->LDS -> barrier A (lgkm only) -> vf loads (V from L2, issued BEFORE
//   STAGE_K so FIFO waits never drain K staging; live only in phase 2) ->
//   STAGE_K(kt+1) (single K buffer: phase1 is its only reader, done by barrier A) ->
//   phase2 (roles 4 c-slices(64) x full q 64, 32 MFMA/wave) -> barrier B vmcnt(0).
// Register budget: phase1 qf64+s32+oacc64 ~ 180; phase2 qf64+vf64+oacc64 ~ 212 < 256.
// Spill tripwire = WRITE_SIZE (16.4MB clean).
// Swizzles: K rows 512B=32 chunks -> ^(row&31); P rows 256B=16 chunks -> ^(row&15).
// 32x32x16 layouts: A[m=lane&31][k=(lane>>5)*8+j]; B[k][n=lane&31]; D col=lane&31,
// row=(r&3)+8*(r>>2)+4*(lane>>5).
__global__ __launch_bounds__(256, 2) void attn_kernel(
    const unsigned short* __restrict__ qT, const unsigned short* __restrict__ kT,
    const unsigned short* __restrict__ vC, unsigned short* __restrict__ aT) {
  __shared__ unsigned short Klds[128 * 256];   // 64KB [m][c], XOR-32 swizzle
  __shared__ unsigned short Plds[64 * 128];    // 16KB [q][m], XOR-16 swizzle
  // total 80KB exactly (2 blocks/CU); lred reuses Plds after the main loop.

  const int tid = threadIdx.x;
  const int w = tid >> 6, lane = tid & 63;    // w in 0..3
  const int l32 = lane & 31, h = lane >> 5;
  const int b = blockIdx.x & 7, qt = blockIdx.x >> 3;   // qt 0..63
  const int qbase = qt * 64;

  const unsigned short* Kb = kT + (size_t)b * NPIX * CH;
  const unsigned short* Vb = vC + (size_t)b * CH * NPIX;

  const int mp  = (w & 1) * 64;   // phase-1 m-pair base (covers [mp, mp+64))
  const int qsl = (w >> 1) * 32;  // phase-1 q-slice (0 or 32)
  const int csl = w * 64;         // phase-2 c-slice base (0..192)

  // Q fragments (B-operand): q = qbase+qsl+l32, k=c = ks*16 + h*8 + j  (64 VGPRs)
  short8 qf[16];
  {
    const unsigned short* qq = qT + ((size_t)(b * NPIX + qbase + qsl + l32)) * CH + h * 8;
#pragma unroll
    for (int ks = 0; ks < 16; ++ks) qf[ks] = *(const short8*)(qq + ks * 16);
  }

  // phase-2 V row pointers (A-operand rows, 16B-contiguous fragments)
  const unsigned short* vrow0 = Vb + (size_t)(csl + l32) * NPIX + h * 8;
  const unsigned short* vrow1 = Vb + (size_t)(csl + 32 + l32) * NPIX + h * 8;

  floatx16 o00 = {}, o01 = {}, o10 = {}, o11 = {};  // [csub][qsub] D[c][q]
  float l_acc = 0.f;

  // K tile stage: 128 rows x 512B; 4 waves -> 32 rows/wave (2 rows per gload16,
  // lanes 0-31 row r, lanes 32-63 row r+1); LDS[row][phys] = K[row][phys ^ (row&31)].
#define STAGE_K(KT)                                                              \
  {                                                                              \
    int m0_ = (KT) * 128;                                                        \
    _Pragma("unroll") for (int j = 0; j < 16; ++j) {                             \
      int r_ = w * 32 + j * 2 + h;                                               \
      gload16(Kb + (size_t)(m0_ + r_) * CH + ((l32 ^ (r_ & 31)) * 8),            \
              &Klds[(w * 32 + j * 2) * 256]);                                    \
    }                                                                            \
  }

  STAGE_K(0);
  asm volatile("s_waitcnt vmcnt(0)\ns_barrier" ::: "memory");

  for (int kt = 0; kt < 32; ++kt) {
    // ---- phase 1: S^T tiles D[m 64][q 32] (two 32x32 m-subtiles, shared qf) ----
    floatx16 s0 = {}, s1 = {};
    {
      const unsigned short* kr0 = &Klds[(mp + l32) * 256];
      const unsigned short* kr1 = &Klds[(mp + 32 + l32) * 256];
      const int mx = l32;   // (mp+l32)&31 == (mp+32+l32)&31 == l32  (mp in {0,64})
#pragma unroll
      for (int ks = 0; ks < 16; ++ks) {
        int off = ((ks * 2 + h) ^ mx) * 8;
        short8 kf0 = *(const short8*)(kr0 + off);
        short8 kf1 = *(const short8*)(kr1 + off);
        s0 = __builtin_amdgcn_mfma_f32_32x32x16_bf16(kf0, qf[ks], s0, 0, 0, 0);
        s1 = __builtin_amdgcn_mfma_f32_32x32x16_bf16(kf1, qf[ks], s1, 0, 0, 0);
      }
    }
    // exp2 + l partial sum (both m-subtiles share q = l32; h-halves differ in m)
    float sum = 0.f;
#pragma unroll
    for (int r = 0; r < 16; ++r) {
      float p0 = exp2f(s0[r]); s0[r] = p0; sum += p0;
      float p1 = exp2f(s1[r]); s1[r] = p1; sum += p1;
    }
    sum += __shfl_xor(sum, 32);
    l_acc += sum;

    // P -> LDS: lane holds (q = qsl+l32, m = mp + sub*32 + 8t + 4h + i) for reg r = 4t+i
    // physical chunk = (logical m-chunk) ^ (q & 15)
    {
      int qrow = qsl + l32;
      int qx = qrow & 15;
      char* Pq = (char*)Plds + qrow * 256 + h * 8;
      int g0 = (w & 1) * 8;   // logical 16B chunk base within the 128-m row
#pragma unroll
      for (int t = 0; t < 4; ++t) {
        uint2 wv;
        wv.x = pk2bf(s0[4 * t], s0[4 * t + 1]);
        wv.y = pk2bf(s0[4 * t + 2], s0[4 * t + 3]);
        *(uint2*)(Pq + (((g0 + t) ^ qx) * 16)) = wv;
        wv.x = pk2bf(s1[4 * t], s1[4 * t + 1]);
        wv.y = pk2bf(s1[4 * t + 2], s1[4 * t + 3]);
        *(uint2*)(Pq + (((g0 + 4 + t) ^ qx) * 16)) = wv;
      }
    }
    // barrier A: P visible + K(kt) reads finished (lgkm only; no VMEM dependency here)
    asm volatile("s_waitcnt lgkmcnt(0)\ns_barrier" ::: "memory");

    // ---- V(kt) register loads: issued BEFORE STAGE_K (FIFO: vf waits leave K
    //      staging in flight). Live only during phase 2 (s0/s1 dead). ----
    short8 vf0[8], vf1[8];
    {
      const unsigned short* v0p = vrow0 + kt * 128;
      const unsigned short* v1p = vrow1 + kt * 128;
#pragma unroll
      for (int ks = 0; ks < 8; ++ks) {
        vf0[ks] = *(const short8*)(v0p + ks * 16);
        vf1[ks] = *(const short8*)(v1p + ks * 16);
      }
    }
    // K(kt+1) staging into the (now fully-read) single K buffer
    if (kt + 1 < 32) STAGE_K(kt + 1);

    // ---- phase 2: O^T += V P^T, wave tile D[c 64][q 64] ----
    {
      const int q0 = l32, q1 = 32 + l32;
      const char* Pb = (const char*)Plds;
#pragma unroll
      for (int ks = 0; ks < 8; ++ks) {
        int sl = ks * 2 + h;
        short8 pf0 = *(const short8*)(Pb + q0 * 256 + ((sl ^ (q0 & 15)) * 16));
        short8 pf1 = *(const short8*)(Pb + q1 * 256 + ((sl ^ (q1 & 15)) * 16));
        o00 = __builtin_amdgcn_mfma_f32_32x32x16_bf16(vf0[ks], pf0, o00, 0, 0, 0);
        o01 = __builtin_amdgcn_mfma_f32_32x32x16_bf16(vf0[ks], pf1, o01, 0, 0, 0);
        o10 = __builtin_amdgcn_mfma_f32_32x32x16_bf16(vf1[ks], pf0, o10, 0, 0, 0);
        o11 = __builtin_amdgcn_mfma_f32_32x32x16_bf16(vf1[ks], pf1, o11, 0, 0, 0);
      }
    }
    // barrier B: P(kt) reads done (next iter rewrites P); K(kt+1) landed.
    // The vmcnt(0) drain is covered by the co-resident second block.
    asm volatile("s_waitcnt vmcnt(0) lgkmcnt(0)\ns_barrier" ::: "memory");
  }
#undef STAGE_K

  // ---- l reconciliation across the 2 m-pair waves per q-slice (Plds -> float[q][2]) ----
  float* lred = (float*)Plds;
  if (lane < 32) lred[(qsl + l32) * 2 + (w & 1)] = l_acc;
  __syncthreads();
  float inv0, inv1;
  {
    const float* lp0 = &lred[(l32) * 2];
    inv0 = 1.f / (lp0[0] + lp0[1]);
    const float* lp1 = &lred[(32 + l32) * 2];
    inv1 = 1.f / (lp1[0] + lp1[1]);
  }

  // ---- store O^T -> aT[q][c] bf16 (explicit accumulators, no array: avoids scratch) ----
  unsigned short* ab = aT + (size_t)b * NPIX * CH;
#define STORE_TILE(OO, CSUB, QSUB, IV)                                           \
  {                                                                              \
    int qg = qbase + (QSUB) * 32 + l32;                                          \
    _Pragma("unroll") for (int t = 0; t < 4; ++t) {                              \
      int c = csl + (CSUB) * 32 + 8 * t + 4 * h;                                 \
      uint2 wv;                                                                  \
      wv.x = pk2bf(OO[4 * t] * (IV), OO[4 * t + 1] * (IV));                      \
      wv.y = pk2bf(OO[4 * t + 2] * (IV), OO[4 * t + 3] * (IV));                  \
      *(uint2*)(ab + (size_t)qg * CH + c) = wv;                                  \
    }                                                                            \
  }
  STORE_TILE(o00, 0, 0, inv0)
  STORE_TILE(o01, 0, 1, inv1)
  STORE_TILE(o10, 1, 0, inv0)
  STORE_TILE(o11, 1, 1, inv1)
#undef STORE_TILE
}

// ---------------- output projection + bias + residual ----------------
__global__ __launch_bounds__(256, 2) void out_gemm(
    const unsigned short* __restrict__ wob, const unsigned short* __restrict__ aT,
    const float* __restrict__ bo, const float* __restrict__ x, float* __restrict__ outp) {
  int nt = blockIdx.x, ot = blockIdx.y, b = blockIdx.z;
  const unsigned short* A = aT + (size_t)b * NPIX * CH;
  int o0 = ot * 128, n0 = nt * 128;

  __shared__ unsigned short As[128 * 64];
  __shared__ unsigned short Bs[128 * 64];

  int tid = threadIdx.x;
  int wave = tid >> 6, lane = tid & 63, quad = lane >> 4, l16 = lane & 15;
  int wm = (wave >> 1) * 64, wn = (wave & 1) * 64;

  floatx4 acc[4][4];
#pragma unroll
  for (int i = 0; i < 4; ++i)
#pragma unroll
    for (int j = 0; j < 4; ++j) acc[i][j] = (floatx4){0.f, 0.f, 0.f, 0.f};

  for (int k0 = 0; k0 < 256; k0 += 64) {
    __syncthreads();
#pragma unroll
    for (int c2 = 0; c2 < 4; ++c2) {
      int row = wave * 32 + c2 * 8 + (lane >> 3);
      int sc = (lane & 7) ^ (row & 7);
      gload16(wob + (size_t)(o0 + row) * CH + k0 + sc * 8, &As[(wave * 32 + c2 * 8) * 64]);
      gload16(A + (size_t)(n0 + row) * CH + k0 + sc * 8, &Bs[(wave * 32 + c2 * 8) * 64]);
    }
    __syncthreads();
#pragma unroll
    for (int s = 0; s < 2; ++s) {
      short8 af[4], bf[4];
#pragma unroll
      for (int i = 0; i < 4; ++i) {
        int m = wm + i * 16 + l16;
        af[i] = *(const short8*)(As + m * 64 + (((s * 4 + quad) ^ (m & 7)) * 8));
        int n = wn + i * 16 + l16;
        bf[i] = *(const short8*)(Bs + n * 64 + (((s * 4 + quad) ^ (n & 7)) * 8));
      }
#pragma unroll
      for (int i = 0; i < 4; ++i)
#pragma unroll
        for (int j = 0; j < 4; ++j)
          acc[i][j] = __builtin_amdgcn_mfma_f32_16x16x32_bf16(af[i], bf[j], acc[i][j], 0, 0, 0);
    }
  }

#pragma unroll
  for (int i = 0; i < 4; ++i)
#pragma unroll
    for (int r = 0; r < 4; ++r) {
      int o = o0 + wm + i * 16 + quad * 4 + r;
      float bb = bo[o];
#pragma unroll
      for (int j = 0; j < 4; ++j) {
        int n = n0 + wn + j * 16 + l16;
        size_t idx = ((size_t)b * CH + o) * NPIX + n;
        outp[idx] = x[idx] + bb + acc[i][j][r];
      }
    }
}

extern "C" void kernel_launch(void* const* d_in, const int* in_sizes, int n_in,
                              void* d_out, int out_size, void* d_ws, size_t ws_size,
                              hipStream_t stream) {
  const float* x   = (const float*)d_in[0];
  const float* gsc = (const float*)d_in[1];
  const float* gbi = (const float*)d_in[2];
  const float* wq  = (const float*)d_in[3];
  const float* bq  = (const float*)d_in[4];
  const float* wk  = (const float*)d_in[5];
  const float* bk  = (const float*)d_in[6];
  const float* wv  = (const float*)d_in[7];
  const float* bv  = (const float*)d_in[8];
  const float* wo  = (const float*)d_in[9];
  const float* bo  = (const float*)d_in[10];
  float* out = (float*)d_out;

  char* ws = (char*)d_ws;
  unsigned short* xnT  = (unsigned short*)(ws);              // 16 MB (dead after qkv)
  unsigned short* qT   = (unsigned short*)(ws + 16777216);   // 16 MB
  unsigned short* kT   = (unsigned short*)(ws + 33554432);   // 16 MB
  unsigned short* vC   = (unsigned short*)(ws + 50331648);   // 16 MB
  unsigned short* wqkv = (unsigned short*)(ws + 67108864);   // 384 KB
  unsigned short* wob  = (unsigned short*)(ws + 67502080);   // 128 KB
  unsigned short* aT   = (unsigned short*)(ws + 67633152);   // 16 MB

  conv_weights_kernel<<<256, 256, 0, stream>>>(wq, wk, wv, wo, wqkv, wob);
  gn_kernel<<<256, 256, 0, stream>>>(x, gsc, gbi, xnT);
  dim3 g1(32, 2, 24);
  qkv_gemm<<<g1, 256, 0, stream>>>(wqkv, xnT, bq, bk, bv, qT, kT, vC);
  attn_kernel<<<512, 256, 0, stream>>>(qT, kT, vC, aT);
  dim3 g3(32, 2, 8);
  out_gemm<<<g3, 256, 0, stream>>>(wob, aT, bo, x, out);
}

// Round 7
// 497.654 us; speedup vs baseline: 1.0734x; 1.0393x over previous
//
#include <hip/hip_runtime.h>

typedef __attribute__((ext_vector_type(8))) short short8;
typedef __attribute__((ext_vector_type(4))) float floatx4;
typedef __attribute__((ext_vector_type(16))) float floatx16;
typedef __attribute__((ext_vector_type(4))) int intx4;

#define NPIX 4096
#define CH 256

static __device__ __forceinline__ unsigned short f2bf(float f) {
  union { float f; unsigned int u; } v; v.f = f;
  unsigned int u = v.u;
  return (unsigned short)((u + 0x7FFFu + ((u >> 16) & 1u)) >> 16);
}

// pack bf16(a) | bf16(b)<<16 : 3 VALU ops (2 int-add round + 1 v_perm)
static __device__ __forceinline__ unsigned int pk2bf(float a, float b) {
  union { float f; unsigned int u; } x, y; x.f = a; y.f = b;
  return __builtin_amdgcn_perm(y.u + 0x8000u, x.u + 0x8000u, 0x07060302u);
}

typedef __attribute__((address_space(3))) unsigned int lds_uint;
typedef const __attribute__((address_space(1))) unsigned int glob_uint;
static __device__ __forceinline__ void gload16(const void* g, void* l) {
  __builtin_amdgcn_global_load_lds((glob_uint*)g, (lds_uint*)l, 16, 0, 0);
}

// ---------------- weights fp32 -> bf16 ----------------
__global__ void conv_weights_kernel(const float* __restrict__ wq, const float* __restrict__ wk,
                                    const float* __restrict__ wv, const float* __restrict__ wo,
                                    unsigned short* __restrict__ wqkv, unsigned short* __restrict__ wob) {
  int i = blockIdx.x * 256 + threadIdx.x;   // 0..65535
  wqkv[i]          = f2bf(wq[i]);
  wqkv[65536 + i]  = f2bf(wk[i]);
  wqkv[131072 + i] = f2bf(wv[i]);
  wob[i]           = f2bf(wo[i]);
}

// ---------------- GroupNorm -> xnT bf16 [b][n][c] ----------------
__global__ __launch_bounds__(256) void gn_kernel(const float* __restrict__ x,
                                                 const float* __restrict__ gsc,
                                                 const float* __restrict__ gbi,
                                                 unsigned short* __restrict__ xnT) {
  int blk = blockIdx.x; int b = blk >> 5; int g = blk & 31;
  int c0 = g * 8;
  const float* xb = x + ((size_t)b * CH + c0) * NPIX;
  int tid = threadIdx.x;
  float s = 0.f, ss = 0.f;
#pragma unroll
  for (int ci = 0; ci < 8; ++ci) {
    const floatx4* p = (const floatx4*)(xb + (size_t)ci * NPIX);
    for (int n4 = tid; n4 < 1024; n4 += 256) {
      floatx4 v = p[n4];
      s += v[0] + v[1] + v[2] + v[3];
      ss += v[0]*v[0] + v[1]*v[1] + v[2]*v[2] + v[3]*v[3];
    }
  }
#pragma unroll
  for (int o = 32; o > 0; o >>= 1) { s += __shfl_down(s, o); ss += __shfl_down(ss, o); }
  __shared__ float red[10];
  int wid = tid >> 6;
  if ((tid & 63) == 0) { red[wid] = s; red[4 + wid] = ss; }
  __syncthreads();
  if (tid == 0) {
    float S = red[0] + red[1] + red[2] + red[3];
    float SS = red[4] + red[5] + red[6] + red[7];
    float mean = S * (1.f / 32768.f);
    float var = SS * (1.f / 32768.f) - mean * mean;
    red[8] = mean; red[9] = rsqrtf(var + 1e-5f);
  }
  __syncthreads();
  float mean = red[8], rstd = red[9];
  float sc[8], bi[8];
#pragma unroll
  for (int ci = 0; ci < 8; ++ci) {
    float scale = gsc[c0 + ci] * rstd;
    sc[ci] = scale;
    bi[ci] = gbi[c0 + ci] - mean * scale;
  }
  for (int n4 = tid; n4 < 1024; n4 += 256) {
    floatx4 v[8];
#pragma unroll
    for (int ci = 0; ci < 8; ++ci) v[ci] = ((const floatx4*)(xb + (size_t)ci * NPIX))[n4];
#pragma unroll
    for (int j = 0; j < 4; ++j) {
      alignas(16) unsigned short tmp[8];
#pragma unroll
      for (int ci = 0; ci < 8; ++ci) tmp[ci] = f2bf(v[ci][j] * sc[ci] + bi[ci]);
      *(intx4*)(xnT + ((size_t)(b * NPIX + n4 * 4 + j)) * CH + c0) = *(const intx4*)tmp;
    }
  }
}

// ---------------- QKV GEMM: D[o,n] = sum_c W[o,c]*xnT[n,c] + bias ----------------
// q pre-scaled by log2e/16 ; q,k written [n][o] bf16 ; v written [o][n] bf16
__global__ __launch_bounds__(256, 2) void qkv_gemm(
    const unsigned short* __restrict__ wqkv, const unsigned short* __restrict__ xnT,
    const float* __restrict__ bq, const float* __restrict__ bk, const float* __restrict__ bv,
    unsigned short* __restrict__ qT, unsigned short* __restrict__ kT, unsigned short* __restrict__ vC) {
  int nt = blockIdx.x, ot = blockIdx.y, bz = blockIdx.z;
  int which = bz % 3, b = bz / 3;
  const unsigned short* W = wqkv + which * 65536;
  const float* bias = which == 0 ? bq : (which == 1 ? bk : bv);
  const unsigned short* X = xnT + (size_t)b * NPIX * CH;
  int o0 = ot * 128, n0 = nt * 128;

  __shared__ unsigned short As[128 * 64];
  __shared__ unsigned short Bs[128 * 64];

  int tid = threadIdx.x;
  int wave = tid >> 6, lane = tid & 63, quad = lane >> 4, l16 = lane & 15;
  int wm = (wave >> 1) * 64, wn = (wave & 1) * 64;

  floatx4 acc[4][4];
#pragma unroll
  for (int i = 0; i < 4; ++i)
#pragma unroll
    for (int j = 0; j < 4; ++j) acc[i][j] = (floatx4){0.f, 0.f, 0.f, 0.f};

  for (int k0 = 0; k0 < 256; k0 += 64) {
    __syncthreads();
#pragma unroll
    for (int c2 = 0; c2 < 4; ++c2) {
      int row = wave * 32 + c2 * 8 + (lane >> 3);
      int sc = (lane & 7) ^ (row & 7);
      gload16(W + (size_t)(o0 + row) * CH + k0 + sc * 8, &As[(wave * 32 + c2 * 8) * 64]);
      gload16(X + (size_t)(n0 + row) * CH + k0 + sc * 8, &Bs[(wave * 32 + c2 * 8) * 64]);
    }
    __syncthreads();
#pragma unroll
    for (int s = 0; s < 2; ++s) {
      short8 af[4], bf[4];
#pragma unroll
      for (int i = 0; i < 4; ++i) {
        int m = wm + i * 16 + l16;
        af[i] = *(const short8*)(As + m * 64 + (((s * 4 + quad) ^ (m & 7)) * 8));
        int n = wn + i * 16 + l16;
        bf[i] = *(const short8*)(Bs + n * 64 + (((s * 4 + quad) ^ (n & 7)) * 8));
      }
#pragma unroll
      for (int i = 0; i < 4; ++i)
#pragma unroll
        for (int j = 0; j < 4; ++j)
          acc[i][j] = __builtin_amdgcn_mfma_f32_16x16x32_bf16(af[i], bf[j], acc[i][j], 0, 0, 0);
    }
  }

  if (which < 2) {
    // 0.0625 * log2(e)
    float qs = (which == 0) ? 0.090168440f : 1.0f;
    unsigned short* outp = (which == 0 ? qT : kT) + (size_t)b * NPIX * CH;
#pragma unroll
    for (int i = 0; i < 4; ++i) {
      int obase = o0 + wm + i * 16 + quad * 4;
      float bias4[4];
#pragma unroll
      for (int r = 0; r < 4; ++r) bias4[r] = bias[obase + r];
#pragma unroll
      for (int j = 0; j < 4; ++j) {
        int n = n0 + wn + j * 16 + l16;
        uint2 pk;
        pk.x = pk2bf((acc[i][j][0] + bias4[0]) * qs, (acc[i][j][1] + bias4[1]) * qs);
        pk.y = pk2bf((acc[i][j][2] + bias4[2]) * qs, (acc[i][j][3] + bias4[3]) * qs);
        *(uint2*)(outp + (size_t)n * CH + obase) = pk;
      }
    }
  } else {
    unsigned short* outp = vC + (size_t)b * CH * NPIX;
#pragma unroll
    for (int i = 0; i < 4; ++i)
#pragma unroll
      for (int r = 0; r < 4; ++r) {
        int o = o0 + wm + i * 16 + quad * 4 + r;
        float bb = bias[o];
#pragma unroll
        for (int j = 0; j < 4; ++j) {
          int n = n0 + wn + j * 16 + l16;
          outp[(size_t)o * NPIX + n] = f2bf(acc[i][j][r] + bb);
        }
      }
  }
}

// ---------------- fused attention: 2 blocks/CU, 4 waves, q-tile 64, KTILE=128 ---------
// Round-7 = round-6 structure with the VGPR cap REMOVED. Rounds 1-6 all ran with
// __launch_bounds__(...,2) which capped the allocator at 128 arch-VGPRs (VGPR_Count
// pinned at 128 every round); any design with live>128 (R1/R5/R6) was force-spilled
// (WRITE_SIZE 30-44MB = scratch). __launch_bounds__(256) lets the allocator use
// ~150-256: o-accumulators go to AGPR space, arch side qf64+vf64+addr fits, granularity
// rounds to 256 -> still 2 waves/SIMD -> 2 blocks/CU co-residency preserved
// (per SIMD: 2 waves x <=256 = 512 = pool; LDS 2 x 80KB = 160KB).
//   grid 512: b = bid&7 (XCD-pinned), qt = bid>>3 (0..63), q-tile 64.
//   LDS = Klds[128*256] 64KB + Plds[64*128] 16KB = 80KB EXACTLY.
// Per iter (32 iters): phase1 (2 m-pairs x 2 q-slices, 32 MFMA/wave) -> softmax ->
//   P->LDS -> barrier A (lgkm only) -> vf loads (V from L2, BEFORE STAGE_K: FIFO waits
//   on vf leave K staging in flight; vf live only in phase 2) -> STAGE_K(kt+1) (single
//   K buffer; phase1 done reading at barrier A) -> phase2 (4 c-slices x q64) ->
//   barrier B vmcnt(0) (covered by the co-resident second block).
// Tripwires: WRITE_SIZE >18MB = spill; Occupancy ~11% = allocator >256 arch.
// Swizzles: K rows 512B=32 chunks -> ^(row&31); P rows 256B=16 chunks -> ^(row&15).
// 32x32x16 layouts: A[m=lane&31][k=(lane>>5)*8+j]; B[k][n=lane&31]; D col=lane&31,
// row=(r&3)+8*(r>>2)+4*(lane>>5).
__global__ __launch_bounds__(256) void attn_kernel(
    const unsigned short* __restrict__ qT, const unsigned short* __restrict__ kT,
    const unsigned short* __restrict__ vC, unsigned short* __restrict__ aT) {
  __shared__ unsigned short Klds[128 * 256];   // 64KB [m][c], XOR-32 swizzle
  __shared__ unsigned short Plds[64 * 128];    // 16KB [q][m], XOR-16 swizzle
  // total 80KB exactly (2 blocks/CU); lred reuses Plds after the main loop.

  const int tid = threadIdx.x;
  const int w = tid >> 6, lane = tid & 63;    // w in 0..3
  const int l32 = lane & 31, h = lane >> 5;
  const int b = blockIdx.x & 7, qt = blockIdx.x >> 3;   // qt 0..63
  const int qbase = qt * 64;

  const unsigned short* Kb = kT + (size_t)b * NPIX * CH;
  const unsigned short* Vb = vC + (size_t)b * CH * NPIX;

  const int mp  = (w & 1) * 64;   // phase-1 m-pair base (covers [mp, mp+64))
  const int qsl = (w >> 1) * 32;  // phase-1 q-slice (0 or 32)
  const int csl = w * 64;         // phase-2 c-slice base (0..192)

  // Q fragments (B-operand): q = qbase+qsl+l32, k=c = ks*16 + h*8 + j  (64 VGPRs)
  short8 qf[16];
  {
    const unsigned short* qq = qT + ((size_t)(b * NPIX + qbase + qsl + l32)) * CH + h * 8;
#pragma unroll
    for (int ks = 0; ks < 16; ++ks) qf[ks] = *(const short8*)(qq + ks * 16);
  }

  // phase-2 V row pointers (A-operand rows, 16B-contiguous fragments)
  const unsigned short* vrow0 = Vb + (size_t)(csl + l32) * NPIX + h * 8;
  const unsigned short* vrow1 = Vb + (size_t)(csl + 32 + l32) * NPIX + h * 8;

  floatx16 o00 = {}, o01 = {}, o10 = {}, o11 = {};  // [csub][qsub] D[c][q]
  float l_acc = 0.f;

  // K tile stage: 128 rows x 512B; 4 waves -> 32 rows/wave (2 rows per gload16,
  // lanes 0-31 row r, lanes 32-63 row r+1); LDS[row][phys] = K[row][phys ^ (row&31)].
#define STAGE_K(KT)                                                              \
  {                                                                              \
    int m0_ = (KT) * 128;                                                        \
    _Pragma("unroll") for (int j = 0; j < 16; ++j) {                             \
      int r_ = w * 32 + j * 2 + h;                                               \
      gload16(Kb + (size_t)(m0_ + r_) * CH + ((l32 ^ (r_ & 31)) * 8),            \
              &Klds[(w * 32 + j * 2) * 256]);                                    \
    }                                                                            \
  }

  STAGE_K(0);
  asm volatile("s_waitcnt vmcnt(0)\ns_barrier" ::: "memory");

  for (int kt = 0; kt < 32; ++kt) {
    // ---- phase 1: S^T tiles D[m 64][q 32] (two 32x32 m-subtiles, shared qf) ----
    floatx16 s0 = {}, s1 = {};
    {
      const unsigned short* kr0 = &Klds[(mp + l32) * 256];
      const unsigned short* kr1 = &Klds[(mp + 32 + l32) * 256];
      const int mx = l32;   // (mp+l32)&31 == (mp+32+l32)&31 == l32  (mp in {0,64})
#pragma unroll
      for (int ks = 0; ks < 16; ++ks) {
        int off = ((ks * 2 + h) ^ mx) * 8;
        short8 kf0 = *(const short8*)(kr0 + off);
        short8 kf1 = *(const short8*)(kr1 + off);
        s0 = __builtin_amdgcn_mfma_f32_32x32x16_bf16(kf0, qf[ks], s0, 0, 0, 0);
        s1 = __builtin_amdgcn_mfma_f32_32x32x16_bf16(kf1, qf[ks], s1, 0, 0, 0);
      }
    }
    // exp2 + l partial sum (both m-subtiles share q = l32; h-halves differ in m)
    float sum = 0.f;
#pragma unroll
    for (int r = 0; r < 16; ++r) {
      float p0 = exp2f(s0[r]); s0[r] = p0; sum += p0;
      float p1 = exp2f(s1[r]); s1[r] = p1; sum += p1;
    }
    sum += __shfl_xor(sum, 32);
    l_acc += sum;

    // P -> LDS: lane holds (q = qsl+l32, m = mp + sub*32 + 8t + 4h + i) for reg r = 4t+i
    // physical chunk = (logical m-chunk) ^ (q & 15)
    {
      int qrow = qsl + l32;
      int qx = qrow & 15;
      char* Pq = (char*)Plds + qrow * 256 + h * 8;
      int g0 = (w & 1) * 8;   // logical 16B chunk base within the 128-m row
#pragma unroll
      for (int t = 0; t < 4; ++t) {
        uint2 wv;
        wv.x = pk2bf(s0[4 * t], s0[4 * t + 1]);
        wv.y = pk2bf(s0[4 * t + 2], s0[4 * t + 3]);
        *(uint2*)(Pq + (((g0 + t) ^ qx) * 16)) = wv;
        wv.x = pk2bf(s1[4 * t], s1[4 * t + 1]);
        wv.y = pk2bf(s1[4 * t + 2], s1[4 * t + 3]);
        *(uint2*)(Pq + (((g0 + 4 + t) ^ qx) * 16)) = wv;
      }
    }
    // barrier A: P visible + K(kt) reads finished (lgkm only; no VMEM dependency here)
    asm volatile("s_waitcnt lgkmcnt(0)\ns_barrier" ::: "memory");

    // ---- V(kt) register loads: issued BEFORE STAGE_K (FIFO: vf waits leave K
    //      staging in flight). Live only during phase 2 (s0/s1 dead). ----
    short8 vf0[8], vf1[8];
    {
      const unsigned short* v0p = vrow0 + kt * 128;
      const unsigned short* v1p = vrow1 + kt * 128;
#pragma unroll
      for (int ks = 0; ks < 8; ++ks) {
        vf0[ks] = *(const short8*)(v0p + ks * 16);
        vf1[ks] = *(const short8*)(v1p + ks * 16);
      }
    }
    // K(kt+1) staging into the (now fully-read) single K buffer
    if (kt + 1 < 32) STAGE_K(kt + 1);

    // ---- phase 2: O^T += V P^T, wave tile D[c 64][q 64] ----
    {
      const int q0 = l32, q1 = 32 + l32;
      const char* Pb = (const char*)Plds;
#pragma unroll
      for (int ks = 0; ks < 8; ++ks) {
        int sl = ks * 2 + h;
        short8 pf0 = *(const short8*)(Pb + q0 * 256 + ((sl ^ (q0 & 15)) * 16));
        short8 pf1 = *(const short8*)(Pb + q1 * 256 + ((sl ^ (q1 & 15)) * 16));
        o00 = __builtin_amdgcn_mfma_f32_32x32x16_bf16(vf0[ks], pf0, o00, 0, 0, 0);
        o01 = __builtin_amdgcn_mfma_f32_32x32x16_bf16(vf0[ks], pf1, o01, 0, 0, 0);
        o10 = __builtin_amdgcn_mfma_f32_32x32x16_bf16(vf1[ks], pf0, o10, 0, 0, 0);
        o11 = __builtin_amdgcn_mfma_f32_32x32x16_bf16(vf1[ks], pf1, o11, 0, 0, 0);
      }
    }
    // barrier B: P(kt) reads done (next iter rewrites P); K(kt+1) landed.
    // The vmcnt(0) drain is covered by the co-resident second block.
    asm volatile("s_waitcnt vmcnt(0) lgkmcnt(0)\ns_barrier" ::: "memory");
  }
#undef STAGE_K

  // ---- l reconciliation across the 2 m-pair waves per q-slice (Plds -> float[q][2]) ----
  float* lred = (float*)Plds;
  if (lane < 32) lred[(qsl + l32) * 2 + (w & 1)] = l_acc;
  __syncthreads();
  float inv0, inv1;
  {
    const float* lp0 = &lred[(l32) * 2];
    inv0 = 1.f / (lp0[0] + lp0[1]);
    const float* lp1 = &lred[(32 + l32) * 2];
    inv1 = 1.f / (lp1[0] + lp1[1]);
  }

  // ---- store O^T -> aT[q][c] bf16 (explicit accumulators, no array: avoids scratch) ----
  unsigned short* ab = aT + (size_t)b * NPIX * CH;
#define STORE_TILE(OO, CSUB, QSUB, IV)                                           \
  {                                                                              \
    int qg = qbase + (QSUB) * 32 + l32;                                          \
    _Pragma("unroll") for (int t = 0; t < 4; ++t) {                              \
      int c = csl + (CSUB) * 32 + 8 * t + 4 * h;                                 \
      uint2 wv;                                                                  \
      wv.x = pk2bf(OO[4 * t] * (IV), OO[4 * t + 1] * (IV));                      \
      wv.y = pk2bf(OO[4 * t + 2] * (IV), OO[4 * t + 3] * (IV));                  \
      *(uint2*)(ab + (size_t)qg * CH + c) = wv;                                  \
    }                                                                            \
  }
  STORE_TILE(o00, 0, 0, inv0)
  STORE_TILE(o01, 0, 1, inv1)
  STORE_TILE(o10, 1, 0, inv0)
  STORE_TILE(o11, 1, 1, inv1)
#undef STORE_TILE
}

// ---------------- output projection + bias + residual ----------------
__global__ __launch_bounds__(256, 2) void out_gemm(
    const unsigned short* __restrict__ wob, const unsigned short* __restrict__ aT,
    const float* __restrict__ bo, const float* __restrict__ x, float* __restrict__ outp) {
  int nt = blockIdx.x, ot = blockIdx.y, b = blockIdx.z;
  const unsigned short* A = aT + (size_t)b * NPIX * CH;
  int o0 = ot * 128, n0 = nt * 128;

  __shared__ unsigned short As[128 * 64];
  __shared__ unsigned short Bs[128 * 64];

  int tid = threadIdx.x;
  int wave = tid >> 6, lane = tid & 63, quad = lane >> 4, l16 = lane & 15;
  int wm = (wave >> 1) * 64, wn = (wave & 1) * 64;

  floatx4 acc[4][4];
#pragma unroll
  for (int i = 0; i < 4; ++i)
#pragma unroll
    for (int j = 0; j < 4; ++j) acc[i][j] = (floatx4){0.f, 0.f, 0.f, 0.f};

  for (int k0 = 0; k0 < 256; k0 += 64) {
    __syncthreads();
#pragma unroll
    for (int c2 = 0; c2 < 4; ++c2) {
      int row = wave * 32 + c2 * 8 + (lane >> 3);
      int sc = (lane & 7) ^ (row & 7);
      gload16(wob + (size_t)(o0 + row) * CH + k0 + sc * 8, &As[(wave * 32 + c2 * 8) * 64]);
      gload16(A + (size_t)(n0 + row) * CH + k0 + sc * 8, &Bs[(wave * 32 + c2 * 8) * 64]);
    }
    __syncthreads();
#pragma unroll
    for (int s = 0; s < 2; ++s) {
      short8 af[4], bf[4];
#pragma unroll
      for (int i = 0; i < 4; ++i) {
        int m = wm + i * 16 + l16;
        af[i] = *(const short8*)(As + m * 64 + (((s * 4 + quad) ^ (m & 7)) * 8));
        int n = wn + i * 16 + l16;
        bf[i] = *(const short8*)(Bs + n * 64 + (((s * 4 + quad) ^ (n & 7)) * 8));
      }
#pragma unroll
      for (int i = 0; i < 4; ++i)
#pragma unroll
        for (int j = 0; j < 4; ++j)
          acc[i][j] = __builtin_amdgcn_mfma_f32_16x16x32_bf16(af[i], bf[j], acc[i][j], 0, 0, 0);
    }
  }

#pragma unroll
  for (int i = 0; i < 4; ++i)
#pragma unroll
    for (int r = 0; r < 4; ++r) {
      int o = o0 + wm + i * 16 + quad * 4 + r;
      float bb = bo[o];
#pragma unroll
      for (int j = 0; j < 4; ++j) {
        int n = n0 + wn + j * 16 + l16;
        size_t idx = ((size_t)b * CH + o) * NPIX + n;
        outp[idx] = x[idx] + bb + acc[i][j][r];
      }
    }
}

extern "C" void kernel_launch(void* const* d_in, const int* in_sizes, int n_in,
                              void* d_out, int out_size, void* d_ws, size_t ws_size,
                              hipStream_t stream) {
  const float* x   = (const float*)d_in[0];
  const float* gsc = (const float*)d_in[1];
  const float* gbi = (const float*)d_in[2];
  const float* wq  = (const float*)d_in[3];
  const float* bq  = (const float*)d_in[4];
  const float* wk  = (const float*)d_in[5];
  const float* bk  = (const float*)d_in[6];
  const float* wv  = (const float*)d_in[7];
  const float* bv  = (const float*)d_in[8];
  const float* wo  = (const float*)d_in[9];
  const float* bo  = (const float*)d_in[10];
  float* out = (float*)d_out;

  char* ws = (char*)d_ws;
  unsigned short* xnT  = (unsigned short*)(ws);              // 16 MB (dead after qkv)
  unsigned short* qT   = (unsigned short*)(ws + 16777216);   // 16 MB
  unsigned short* kT   = (unsigned short*)(ws + 33554432);   // 16 MB
  unsigned short* vC   = (unsigned short*)(ws + 50331648);   // 16 MB
  unsigned short* wqkv = (unsigned short*)(ws + 67108864);   // 384 KB
  unsigned short* wob  = (unsigned short*)(ws + 67502080);   // 128 KB
  unsigned short* aT   = (unsigned short*)(ws + 67633152);   // 16 MB

  conv_weights_kernel<<<256, 256, 0, stream>>>(wq, wk, wv, wo, wqkv, wob);
  gn_kernel<<<256, 256, 0, stream>>>(x, gsc, gbi, xnT);
  dim3 g1(32, 2, 24);
  qkv_gemm<<<g1, 256, 0, stream>>>(wqkv, xnT, bq, bk, bv, qT, kT, vC);
  attn_kernel<<<512, 256, 0, stream>>>(qT, kT, vC, aT);
  dim3 g3(32, 2, 8);
  out_gemm<<<g3, 256, 0, stream>>>(wob, aT, bo, x, out);
}

// Round 8
// 342.689 us; speedup vs baseline: 1.5588x; 1.4522x over previous
//
#include <hip/hip_runtime.h>

typedef __attribute__((ext_vector_type(8))) short short8;
typedef __attribute__((ext_vector_type(4))) float floatx4;
typedef __attribute__((ext_vector_type(16))) float floatx16;
typedef __attribute__((ext_vector_type(4))) int intx4;

#define NPIX 4096
#define CH 256

static __device__ __forceinline__ unsigned short f2bf(float f) {
  union { float f; unsigned int u; } v; v.f = f;
  unsigned int u = v.u;
  return (unsigned short)((u + 0x7FFFu + ((u >> 16) & 1u)) >> 16);
}

// pack bf16(a) | bf16(b)<<16 : 3 VALU ops (2 int-add round + 1 v_perm)
static __device__ __forceinline__ unsigned int pk2bf(float a, float b) {
  union { float f; unsigned int u; } x, y; x.f = a; y.f = b;
  return __builtin_amdgcn_perm(y.u + 0x8000u, x.u + 0x8000u, 0x07060302u);
}

typedef __attribute__((address_space(3))) unsigned int lds_uint;
typedef const __attribute__((address_space(1))) unsigned int glob_uint;
static __device__ __forceinline__ void gload16(const void* g, void* l) {
  __builtin_amdgcn_global_load_lds((glob_uint*)g, (lds_uint*)l, 16, 0, 0);
}

// ---------------- GroupNorm -> xnT bf16 [b][n][c]  (+ fused weight fp32->bf16) -------
// Round-8: conv_weights_kernel folded in (grid 256 x 256 covers the 65536 weight elems
// exactly; independent work, saves one dispatch).
__global__ __launch_bounds__(256) void gn_kernel(const float* __restrict__ x,
                                                 const float* __restrict__ gsc,
                                                 const float* __restrict__ gbi,
                                                 unsigned short* __restrict__ xnT,
                                                 const float* __restrict__ wq,
                                                 const float* __restrict__ wk,
                                                 const float* __restrict__ wv,
                                                 const float* __restrict__ wo,
                                                 unsigned short* __restrict__ wqkv,
                                                 unsigned short* __restrict__ wob) {
  int blk = blockIdx.x; int b = blk >> 5; int g = blk & 31;
  int c0 = g * 8;
  int tid = threadIdx.x;
  {  // fused weights conversion: 256 blocks x 256 threads = 65536 elements
    int i = blk * 256 + tid;
    wqkv[i]          = f2bf(wq[i]);
    wqkv[65536 + i]  = f2bf(wk[i]);
    wqkv[131072 + i] = f2bf(wv[i]);
    wob[i]           = f2bf(wo[i]);
  }
  const float* xb = x + ((size_t)b * CH + c0) * NPIX;
  float s = 0.f, ss = 0.f;
#pragma unroll
  for (int ci = 0; ci < 8; ++ci) {
    const floatx4* p = (const floatx4*)(xb + (size_t)ci * NPIX);
    for (int n4 = tid; n4 < 1024; n4 += 256) {
      floatx4 v = p[n4];
      s += v[0] + v[1] + v[2] + v[3];
      ss += v[0]*v[0] + v[1]*v[1] + v[2]*v[2] + v[3]*v[3];
    }
  }
#pragma unroll
  for (int o = 32; o > 0; o >>= 1) { s += __shfl_down(s, o); ss += __shfl_down(ss, o); }
  __shared__ float red[10];
  int wid = tid >> 6;
  if ((tid & 63) == 0) { red[wid] = s; red[4 + wid] = ss; }
  __syncthreads();
  if (tid == 0) {
    float S = red[0] + red[1] + red[2] + red[3];
    float SS = red[4] + red[5] + red[6] + red[7];
    float mean = S * (1.f / 32768.f);
    float var = SS * (1.f / 32768.f) - mean * mean;
    red[8] = mean; red[9] = rsqrtf(var + 1e-5f);
  }
  __syncthreads();
  float mean = red[8], rstd = red[9];
  float sc[8], bi[8];
#pragma unroll
  for (int ci = 0; ci < 8; ++ci) {
    float scale = gsc[c0 + ci] * rstd;
    sc[ci] = scale;
    bi[ci] = gbi[c0 + ci] - mean * scale;
  }
  for (int n4 = tid; n4 < 1024; n4 += 256) {
    floatx4 v[8];
#pragma unroll
    for (int ci = 0; ci < 8; ++ci) v[ci] = ((const floatx4*)(xb + (size_t)ci * NPIX))[n4];
#pragma unroll
    for (int j = 0; j < 4; ++j) {
      alignas(16) unsigned short tmp[8];
#pragma unroll
      for (int ci = 0; ci < 8; ++ci) tmp[ci] = f2bf(v[ci][j] * sc[ci] + bi[ci]);
      *(intx4*)(xnT + ((size_t)(b * NPIX + n4 * 4 + j)) * CH + c0) = *(const intx4*)tmp;
    }
  }
}

// ---------------- QKV GEMM: D[o,n] = sum_c W[o,c]*xnT[n,c] + bias ----------------
// q pre-scaled by log2e/16 ; q,k written [n][o] bf16 ; v written [o][n] bf16
__global__ __launch_bounds__(256, 2) void qkv_gemm(
    const unsigned short* __restrict__ wqkv, const unsigned short* __restrict__ xnT,
    const float* __restrict__ bq, const float* __restrict__ bk, const float* __restrict__ bv,
    unsigned short* __restrict__ qT, unsigned short* __restrict__ kT, unsigned short* __restrict__ vC) {
  int nt = blockIdx.x, ot = blockIdx.y, bz = blockIdx.z;
  int which = bz % 3, b = bz / 3;
  const unsigned short* W = wqkv + which * 65536;
  const float* bias = which == 0 ? bq : (which == 1 ? bk : bv);
  const unsigned short* X = xnT + (size_t)b * NPIX * CH;
  int o0 = ot * 128, n0 = nt * 128;

  __shared__ unsigned short As[128 * 64];
  __shared__ unsigned short Bs[128 * 64];

  int tid = threadIdx.x;
  int wave = tid >> 6, lane = tid & 63, quad = lane >> 4, l16 = lane & 15;
  int wm = (wave >> 1) * 64, wn = (wave & 1) * 64;

  floatx4 acc[4][4];
#pragma unroll
  for (int i = 0; i < 4; ++i)
#pragma unroll
    for (int j = 0; j < 4; ++j) acc[i][j] = (floatx4){0.f, 0.f, 0.f, 0.f};

  for (int k0 = 0; k0 < 256; k0 += 64) {
    __syncthreads();
#pragma unroll
    for (int c2 = 0; c2 < 4; ++c2) {
      int row = wave * 32 + c2 * 8 + (lane >> 3);
      int sc = (lane & 7) ^ (row & 7);
      gload16(W + (size_t)(o0 + row) * CH + k0 + sc * 8, &As[(wave * 32 + c2 * 8) * 64]);
      gload16(X + (size_t)(n0 + row) * CH + k0 + sc * 8, &Bs[(wave * 32 + c2 * 8) * 64]);
    }
    __syncthreads();
#pragma unroll
    for (int s = 0; s < 2; ++s) {
      short8 af[4], bf[4];
#pragma unroll
      for (int i = 0; i < 4; ++i) {
        int m = wm + i * 16 + l16;
        af[i] = *(const short8*)(As + m * 64 + (((s * 4 + quad) ^ (m & 7)) * 8));
        int n = wn + i * 16 + l16;
        bf[i] = *(const short8*)(Bs + n * 64 + (((s * 4 + quad) ^ (n & 7)) * 8));
      }
#pragma unroll
      for (int i = 0; i < 4; ++i)
#pragma unroll
        for (int j = 0; j < 4; ++j)
          acc[i][j] = __builtin_amdgcn_mfma_f32_16x16x32_bf16(af[i], bf[j], acc[i][j], 0, 0, 0);
    }
  }

  if (which < 2) {
    // 0.0625 * log2(e)
    float qs = (which == 0) ? 0.090168440f : 1.0f;
    unsigned short* outp = (which == 0 ? qT : kT) + (size_t)b * NPIX * CH;
#pragma unroll
    for (int i = 0; i < 4; ++i) {
      int obase = o0 + wm + i * 16 + quad * 4;
      float bias4[4];
#pragma unroll
      for (int r = 0; r < 4; ++r) bias4[r] = bias[obase + r];
#pragma unroll
      for (int j = 0; j < 4; ++j) {
        int n = n0 + wn + j * 16 + l16;
        uint2 pk;
        pk.x = pk2bf((acc[i][j][0] + bias4[0]) * qs, (acc[i][j][1] + bias4[1]) * qs);
        pk.y = pk2bf((acc[i][j][2] + bias4[2]) * qs, (acc[i][j][3] + bias4[3]) * qs);
        *(uint2*)(outp + (size_t)n * CH + obase) = pk;
      }
    }
  } else {
    unsigned short* outp = vC + (size_t)b * CH * NPIX;
#pragma unroll
    for (int i = 0; i < 4; ++i)
#pragma unroll
      for (int r = 0; r < 4; ++r) {
        int o = o0 + wm + i * 16 + quad * 4 + r;
        float bb = bias[o];
#pragma unroll
        for (int j = 0; j < 4; ++j) {
          int n = n0 + wn + j * 16 + l16;
          outp[(size_t)o * NPIX + n] = f2bf(acc[i][j][r] + bb);
        }
      }
  }
}

// ---------------- fused attention: 1 block/CU, 8 waves, q-tile 128, 32x32x16 MFMA ------
// ROUND-8 = the round-0 harness-proven structure (170.6us) + ONE verified fix: the K
// swizzle widened from ^(row&7) to ^(row&31). K rows are 512B = 32 x 16B chunks; the
// row index contributes nothing to the bank (512 == 0 mod 128B), so the old 8-wide XOR
// left phase-1 kf ds_read_b128 4-way bank-conflicted (half of the 1.888e7 conflict
// cycles). Full-width XOR -> 32 distinct chunks across the 32 reading lanes ->
// conflict-free. Same both-sides edit verified correct in round 3. V/P rows (128B = 8
// chunks) are already full-width (4-way floor is structural for them).
// grid 256: b = bid&7 (XCD-pinned), qt = bid>>3. KTILE=64, 64 iters, dbuf K/V staging.
// Phase1 (S^T = K·Q^T, 32x32 tiles): wave -> m-slice (w&1)*32, q-slice (w>>1)*32.
// exp2 (log2e folded into Q), no max-subtraction; P bf16 -> LDS.
// Phase2 (O^T += V·P^T): wave -> c-slice (w&3)*64, q-half (w>>2)*64.
// 32x32x16 layouts: A[m=lane&31][k=(lane>>5)*8+j]; B[k][n=lane&31]; D col=lane&31,
// row=(r&3)+8*(r>>2)+4*(lane>>5).
__global__ __launch_bounds__(512, 2) void attn_kernel(
    const unsigned short* __restrict__ qT, const unsigned short* __restrict__ kT,
    const unsigned short* __restrict__ vC, unsigned short* __restrict__ aT) {
  __shared__ unsigned short Klds[2][64 * 256];   // 2 x 32KB, [m][c], XOR-32 swizzle
  __shared__ unsigned short Vlds[2][256 * 64];   // 2 x 32KB, [c][m], XOR-8 swizzle
  __shared__ unsigned short Plds[128 * 64];      // 16KB, [q][m], XOR-8 swizzle
  __shared__ float lred[128][2];

  const int tid = threadIdx.x;
  const int w = tid >> 6, lane = tid & 63;
  const int l32 = lane & 31, h = lane >> 5;
  const int b = blockIdx.x & 7, qt = blockIdx.x >> 3;
  const int qbase = qt * 128;

  const unsigned short* Kb = kT + (size_t)b * NPIX * CH;
  const unsigned short* Vb = vC + (size_t)b * CH * NPIX;

  const int msl = (w & 1) * 32, qsl = (w >> 1) * 32;   // phase-1 role
  const int csl = (w & 3) * 64, qh = (w >> 2) * 64;    // phase-2 role

  // Q fragments (B-operand): q = qbase+qsl+l32, k=c = s*16 + h*8 + j
  short8 qf[16];
  {
    const unsigned short* qp = qT + ((size_t)(b * NPIX + qbase + qsl + l32)) * CH + h * 8;
#pragma unroll
    for (int s = 0; s < 16; ++s) qf[s] = *(const short8*)(qp + s * 16);
  }

  floatx16 oacc[2][2] = {};   // [csub][qsub] -> D[c][q] 32x32 each
  float l_acc = 0.f;

  // ---- staging: waves 0-3 stage K rows [w*16,w*16+16); waves 4-7 stage V rows ----
  // K source chunk = (lane&31) ^ (r0&31)  [full-width, round-8 fix]
#define STAGE(KT)                                                                         \
  {                                                                                       \
    int m0_ = (KT) * 64;                                                                  \
    int bb_ = (KT) & 1;                                                                   \
    if (w < 4) {                                                                          \
      _Pragma("unroll") for (int j = 0; j < 8; ++j) {                                     \
        int r0 = w * 16 + j * 2 + (lane >> 5);                                            \
        gload16(Kb + (size_t)(m0_ + r0) * CH + (((lane & 31) ^ (r0 & 31)) * 8),           \
                &Klds[bb_][(w * 16 + j * 2) * 256]);                                      \
      }                                                                                   \
    } else {                                                                              \
      _Pragma("unroll") for (int j = 0; j < 8; ++j) {                                     \
        int c_ = (w - 4) * 64 + j * 8 + (lane >> 3);                                      \
        gload16(Vb + (size_t)c_ * NPIX + m0_ + (((lane & 7) ^ (c_ & 7)) * 8),             \
                &Vlds[bb_][((w - 4) * 64 + j * 8) * 64]);                                 \
      }                                                                                   \
    }                                                                                     \
  }

  STAGE(0);

  for (int kt = 0; kt < 64; ++kt) {
    const int buf = kt & 1;
    // full barrier: staging for kt (issued one iter ago) must be complete
    asm volatile("s_waitcnt vmcnt(0) lgkmcnt(0)\ns_barrier" ::: "memory");
    if (kt + 1 < 64) STAGE(kt + 1);

    // ---- phase 1: S^T 32x32 tile D[m][q] ----
    floatx16 sacc = {};
    {
      const int m = msl + l32;
      const unsigned short* kr = &Klds[buf][m * 256];
      const int mx = m & 31;   // full-width XOR (round-8 fix; was m & 7)
#pragma unroll
      for (int s = 0; s < 16; ++s) {
        short8 kf = *(const short8*)(kr + (((s * 2 + h) ^ mx) * 8));
        sacc = __builtin_amdgcn_mfma_f32_32x32x16_bf16(kf, qf[s], sacc, 0, 0, 0);
      }
    }
    // exp2 + l partial sum (all 16 regs share q = l32; halves differ in m)
    float sum = 0.f;
#pragma unroll
    for (int r = 0; r < 16; ++r) {
      float p = exp2f(sacc[r]);
      sacc[r] = p; sum += p;
    }
    sum += __shfl_xor(sum, 32);
    l_acc += sum;

    // P -> LDS: lane holds (q = qsl+l32, m = msl + 8*t + 4*h + i) for reg r = 4t+i
    {
      int qrow = qsl + l32;
#pragma unroll
      for (int t = 0; t < 4; ++t) {
        int phys = ((msl >> 3) + t) ^ (qrow & 7);
        uint2 wv;
        wv.x = pk2bf(sacc[4 * t], sacc[4 * t + 1]);
        wv.y = pk2bf(sacc[4 * t + 2], sacc[4 * t + 3]);
        *(uint2*)&Plds[qrow * 64 + phys * 8 + h * 4] = wv;
      }
    }
    // LDS-only barrier: P visible; does NOT drain the in-flight prefetch (vmcnt)
    asm volatile("s_waitcnt lgkmcnt(0)\ns_barrier" ::: "memory");

    // ---- phase 2: O^T += V P^T (32x32 tiles) ----
#pragma unroll
    for (int mstep = 0; mstep < 4; ++mstep) {
      short8 pf[2], vf[2];
#pragma unroll
      for (int qsub = 0; qsub < 2; ++qsub) {
        int q = qh + qsub * 32 + l32;
        pf[qsub] = *(const short8*)&Plds[q * 64 + (((mstep * 2 + h) ^ (q & 7)) * 8)];
      }
#pragma unroll
      for (int csub = 0; csub < 2; ++csub) {
        int c = csl + csub * 32 + l32;
        vf[csub] = *(const short8*)&Vlds[buf][c * 64 + (((mstep * 2 + h) ^ (c & 7)) * 8)];
      }
#pragma unroll
      for (int csub = 0; csub < 2; ++csub)
#pragma unroll
        for (int qsub = 0; qsub < 2; ++qsub)
          oacc[csub][qsub] =
              __builtin_amdgcn_mfma_f32_32x32x16_bf16(vf[csub], pf[qsub], oacc[csub][qsub], 0, 0, 0);
    }
  }
#undef STAGE

  // ---- l reconciliation across the two m-slice waves per q-slice ----
  if (lane < 32) lred[qsl + l32][w & 1] = l_acc;
  __syncthreads();
  float inv[2];
#pragma unroll
  for (int qsub = 0; qsub < 2; ++qsub) {
    int q = qh + qsub * 32 + l32;
    inv[qsub] = 1.f / (lred[q][0] + lred[q][1]);
  }
  // ---- store O^T -> aT[q][c] bf16 ----
  unsigned short* ab = aT + (size_t)b * NPIX * CH;
#pragma unroll
  for (int csub = 0; csub < 2; ++csub)
#pragma unroll
    for (int qsub = 0; qsub < 2; ++qsub) {
      int qg = qbase + qh + qsub * 32 + l32;
      float iv = inv[qsub];
#pragma unroll
      for (int t = 0; t < 4; ++t) {
        int c = csl + csub * 32 + 8 * t + 4 * h;
        uint2 wv;
        wv.x = pk2bf(oacc[csub][qsub][4 * t] * iv, oacc[csub][qsub][4 * t + 1] * iv);
        wv.y = pk2bf(oacc[csub][qsub][4 * t + 2] * iv, oacc[csub][qsub][4 * t + 3] * iv);
        *(uint2*)(ab + (size_t)qg * CH + c) = wv;
      }
    }
}

// ---------------- output projection + bias + residual ----------------
__global__ __launch_bounds__(256, 2) void out_gemm(
    const unsigned short* __restrict__ wob, const unsigned short* __restrict__ aT,
    const float* __restrict__ bo, const float* __restrict__ x, float* __restrict__ outp) {
  int nt = blockIdx.x, ot = blockIdx.y, b = blockIdx.z;
  const unsigned short* A = aT + (size_t)b * NPIX * CH;
  int o0 = ot * 128, n0 = nt * 128;

  __shared__ unsigned short As[128 * 64];
  __shared__ unsigned short Bs[128 * 64];

  int tid = threadIdx.x;
  int wave = tid >> 6, lane = tid & 63, quad = lane >> 4, l16 = lane & 15;
  int wm = (wave >> 1) * 64, wn = (wave & 1) * 64;

  floatx4 acc[4][4];
#pragma unroll
  for (int i = 0; i < 4; ++i)
#pragma unroll
    for (int j = 0; j < 4; ++j) acc[i][j] = (floatx4){0.f, 0.f, 0.f, 0.f};

  for (int k0 = 0; k0 < 256; k0 += 64) {
    __syncthreads();
#pragma unroll
    for (int c2 = 0; c2 < 4; ++c2) {
      int row = wave * 32 + c2 * 8 + (lane >> 3);
      int sc = (lane & 7) ^ (row & 7);
      gload16(wob + (size_t)(o0 + row) * CH + k0 + sc * 8, &As[(wave * 32 + c2 * 8) * 64]);
      gload16(A + (size_t)(n0 + row) * CH + k0 + sc * 8, &Bs[(wave * 32 + c2 * 8) * 64]);
    }
    __syncthreads();
#pragma unroll
    for (int s = 0; s < 2; ++s) {
      short8 af[4], bf[4];
#pragma unroll
      for (int i = 0; i < 4; ++i) {
        int m = wm + i * 16 + l16;
        af[i] = *(const short8*)(As + m * 64 + (((s * 4 + quad) ^ (m & 7)) * 8));
        int n = wn + i * 16 + l16;
        bf[i] = *(const short8*)(Bs + n * 64 + (((s * 4 + quad) ^ (n & 7)) * 8));
      }
#pragma unroll
      for (int i = 0; i < 4; ++i)
#pragma unroll
        for (int j = 0; j < 4; ++j)
          acc[i][j] = __builtin_amdgcn_mfma_f32_16x16x32_bf16(af[i], bf[j], acc[i][j], 0, 0, 0);
    }
  }

#pragma unroll
  for (int i = 0; i < 4; ++i)
#pragma unroll
    for (int r = 0; r < 4; ++r) {
      int o = o0 + wm + i * 16 + quad * 4 + r;
      float bb = bo[o];
#pragma unroll
      for (int j = 0; j < 4; ++j) {
        int n = n0 + wn + j * 16 + l16;
        size_t idx = ((size_t)b * CH + o) * NPIX + n;
        outp[idx] = x[idx] + bb + acc[i][j][r];
      }
    }
}

extern "C" void kernel_launch(void* const* d_in, const int* in_sizes, int n_in,
                              void* d_out, int out_size, void* d_ws, size_t ws_size,
                              hipStream_t stream) {
  const float* x   = (const float*)d_in[0];
  const float* gsc = (const float*)d_in[1];
  const float* gbi = (const float*)d_in[2];
  const float* wq  = (const float*)d_in[3];
  const float* bq  = (const float*)d_in[4];
  const float* wk  = (const float*)d_in[5];
  const float* bk  = (const float*)d_in[6];
  const float* wv  = (const float*)d_in[7];
  const float* bv  = (const float*)d_in[8];
  const float* wo  = (const float*)d_in[9];
  const float* bo  = (const float*)d_in[10];
  float* out = (float*)d_out;

  char* ws = (char*)d_ws;
  unsigned short* xnT  = (unsigned short*)(ws);              // 16 MB (dead after qkv)
  unsigned short* qT   = (unsigned short*)(ws + 16777216);   // 16 MB
  unsigned short* kT   = (unsigned short*)(ws + 33554432);   // 16 MB
  unsigned short* vC   = (unsigned short*)(ws + 50331648);   // 16 MB
  unsigned short* wqkv = (unsigned short*)(ws + 67108864);   // 384 KB
  unsigned short* wob  = (unsigned short*)(ws + 67502080);   // 128 KB
  unsigned short* aT   = (unsigned short*)(ws + 67633152);   // 16 MB

  gn_kernel<<<256, 256, 0, stream>>>(x, gsc, gbi, xnT, wq, wk, wv, wo, wqkv, wob);
  dim3 g1(32, 2, 24);
  qkv_gemm<<<g1, 256, 0, stream>>>(wqkv, xnT, bq, bk, bv, qT, kT, vC);
  attn_kernel<<<256, 512, 0, stream>>>(qT, kT, vC, aT);
  dim3 g3(32, 2, 8);
  out_gemm<<<g3, 256, 0, stream>>>(wob, aT, bo, x, out);
}